// Round 1
// baseline (169.315 us; speedup 1.0000x reference)
//
#include <hip/hip_runtime.h>
#include <math.h>

#define IN_F   1024
#define OUT_F  1024
#define TASK_D 256
#define RANK   8
#define HID    64
// SCALING = ALPHA / RANK = 8.0 / 8 = 1.0  (folded in as identity)

__device__ __forceinline__ float gelu_exact(float v) {
    // jax.nn.gelu(approximate=False) = 0.5*v*(1+erf(v/sqrt(2)))
    return 0.5f * v * (1.0f + erff(v * 0.70710678118654752f));
}

// ---------------------------------------------------------------------------
// Kernel 1: generate vec_a (4 x OUT_F*RANK) and vec_b (4 x RANK*IN_F) into ws.
// Blocks 0..31 handle gen_a (256 output rows each), blocks 32..63 gen_b.
// Each block redundantly computes h[4][64] (tiny), then 256 threads each
// compute one W2 row's dot with all 4 task h-vectors (W2 row read once).
// ---------------------------------------------------------------------------
__global__ __launch_bounds__(256) void gen_kernel(
    const float* __restrict__ task_emb,
    const float* __restrict__ Wa1, const float* __restrict__ ba1,
    const float* __restrict__ Wa2, const float* __restrict__ ba2,
    const float* __restrict__ Wb1, const float* __restrict__ bb1,
    const float* __restrict__ Wb2, const float* __restrict__ bb2,
    float* __restrict__ vec_a, float* __restrict__ vec_b)
{
    const int gen   = blockIdx.x >> 5;            // 0 -> a, 1 -> b
    const int obase = (blockIdx.x & 31) * 256;    // W2 output-row base
    const float* __restrict__ W1  = gen ? Wb1 : Wa1;
    const float* __restrict__ b1  = gen ? bb1 : ba1;
    const float* __restrict__ W2  = gen ? Wb2 : Wa2;
    const float* __restrict__ b2  = gen ? bb2 : ba2;
    float* __restrict__ vec       = gen ? vec_b : vec_a;

    __shared__ float hs[4][HID];
    {
        const int t = threadIdx.x >> 6;   // task 0..3
        const int j = threadIdx.x & 63;   // hidden unit 0..63
        const float4* te = (const float4*)(task_emb + t * TASK_D);
        const float4* w  = (const float4*)(W1 + j * TASK_D);
        float acc = 0.f;
        #pragma unroll
        for (int d = 0; d < TASK_D / 4; ++d) {
            float4 a = te[d], b = w[d];
            acc += a.x * b.x + a.y * b.y + a.z * b.z + a.w * b.w;
        }
        hs[t][j] = gelu_exact(acc + b1[j]);
    }
    __syncthreads();

    const int o = obase + threadIdx.x;                 // 0..8191
    const float4* w2 = (const float4*)(W2 + (size_t)o * HID);
    float acc0 = 0.f, acc1 = 0.f, acc2 = 0.f, acc3 = 0.f;
    #pragma unroll
    for (int k = 0; k < HID / 4; ++k) {
        float4 w = w2[k];
        const int kb = 4 * k;
        acc0 += hs[0][kb] * w.x + hs[0][kb+1] * w.y + hs[0][kb+2] * w.z + hs[0][kb+3] * w.w;
        acc1 += hs[1][kb] * w.x + hs[1][kb+1] * w.y + hs[1][kb+2] * w.z + hs[1][kb+3] * w.w;
        acc2 += hs[2][kb] * w.x + hs[2][kb+1] * w.y + hs[2][kb+2] * w.z + hs[2][kb+3] * w.w;
        acc3 += hs[3][kb] * w.x + hs[3][kb+1] * w.y + hs[3][kb+2] * w.z + hs[3][kb+3] * w.w;
    }
    const float bb = b2[o];
    vec[0 * 8192 + o] = acc0 + bb;
    vec[1 * 8192 + o] = acc1 + bb;
    vec[2 * 8192 + o] = acc2 + bb;
    vec[3 * 8192 + o] = acc3 + bb;
}

// ---------------------------------------------------------------------------
// Kernel 2: per-row LoRA apply. One 64-lane wave per row (4 waves / block).
//   tmp[r] = sum_k x[row,k] * b[t,r,k]        (butterfly shuffle reduction)
//   out[row,o] = base_out[row,o] + sum_r tmp[r] * a[t,o,r]
// All x / base_out / out accesses are coalesced float4. vec_a/vec_b (256 KB
// total) are L2-resident.
// ---------------------------------------------------------------------------
__global__ __launch_bounds__(256) void apply_kernel(
    const float* __restrict__ x, const float* __restrict__ base_out,
    const float* __restrict__ vec_a, const float* __restrict__ vec_b,
    float* __restrict__ out)
{
    const int wave = threadIdx.x >> 6;
    const int lane = threadIdx.x & 63;
    const int row  = blockIdx.x * 4 + wave;
    const int t    = row & 3;                       // task_eff[i] = task_emb[i % 4]

    const float* __restrict__ xr = x + (size_t)row * IN_F;
    const float* __restrict__ bt = vec_b + (size_t)t * (RANK * IN_F);

    float acc[RANK];
    #pragma unroll
    for (int r = 0; r < RANK; ++r) acc[r] = 0.f;

    #pragma unroll
    for (int c = 0; c < IN_F / 256; ++c) {          // 4 chunks of 256 floats
        const int k = c * 256 + lane * 4;
        const float4 xv = *(const float4*)(xr + k);
        #pragma unroll
        for (int r = 0; r < RANK; ++r) {
            const float4 bv = *(const float4*)(bt + r * IN_F + k);
            acc[r] += xv.x * bv.x + xv.y * bv.y + xv.z * bv.z + xv.w * bv.w;
        }
    }

    // butterfly reduce each acc[r] across the 64-lane wave
    #pragma unroll
    for (int off = 32; off > 0; off >>= 1) {
        #pragma unroll
        for (int r = 0; r < RANK; ++r)
            acc[r] += __shfl_xor(acc[r], off, 64);
    }

    const float* __restrict__ at = vec_a + (size_t)t * (OUT_F * RANK);
    const float* __restrict__ br = base_out + (size_t)row * OUT_F;
    float* __restrict__ orow     = out + (size_t)row * OUT_F;

    #pragma unroll
    for (int c = 0; c < OUT_F / 256; ++c) {
        const int o = c * 256 + lane * 4;
        const float4 bo = *(const float4*)(br + o);
        float res[4];
        const float bof[4] = { bo.x, bo.y, bo.z, bo.w };
        #pragma unroll
        for (int q = 0; q < 4; ++q) {
            const float4 a0 = *(const float4*)(at + (size_t)(o + q) * RANK);
            const float4 a1 = *(const float4*)(at + (size_t)(o + q) * RANK + 4);
            res[q] = bof[q]
                   + acc[0] * a0.x + acc[1] * a0.y + acc[2] * a0.z + acc[3] * a0.w
                   + acc[4] * a1.x + acc[5] * a1.y + acc[6] * a1.z + acc[7] * a1.w;
        }
        float4 rv = { res[0], res[1], res[2], res[3] };
        *(float4*)(orow + o) = rv;
    }
}

extern "C" void kernel_launch(void* const* d_in, const int* in_sizes, int n_in,
                              void* d_out, int out_size, void* d_ws, size_t ws_size,
                              hipStream_t stream) {
    const float* x        = (const float*)d_in[0];
    const float* base_out = (const float*)d_in[1];
    const float* task_emb = (const float*)d_in[2];
    const float* Wa1      = (const float*)d_in[3];
    const float* ba1      = (const float*)d_in[4];
    const float* Wa2      = (const float*)d_in[5];
    const float* ba2      = (const float*)d_in[6];
    const float* Wb1      = (const float*)d_in[7];
    const float* bb1      = (const float*)d_in[8];
    const float* Wb2      = (const float*)d_in[9];
    const float* bb2      = (const float*)d_in[10];
    float* out   = (float*)d_out;

    float* vec_a = (float*)d_ws;                      // 4 * 8192 floats = 128 KB
    float* vec_b = vec_a + 4 * OUT_F * RANK;          // 4 * 8192 floats = 128 KB

    const int b_eff = in_sizes[0] / IN_F;             // 8192

    gen_kernel<<<64, 256, 0, stream>>>(task_emb, Wa1, ba1, Wa2, ba2,
                                       Wb1, bb1, Wb2, bb2, vec_a, vec_b);
    apply_kernel<<<b_eff / 4, 256, 0, stream>>>(x, base_out, vec_a, vec_b, out);
}

// Round 2
// 137.148 us; speedup vs baseline: 1.2345x; 1.2345x over previous
//
#include <hip/hip_runtime.h>
#include <math.h>

#define IN_F   1024
#define OUT_F  1024
#define TASK_D 256
#define RANK   8
#define HID    64
// SCALING = ALPHA / RANK = 1.0 (identity)

__device__ __forceinline__ float gelu_exact(float v) {
    return 0.5f * v * (1.0f + erff(v * 0.70710678118654752f));
}

// ---------------------------------------------------------------------------
// Kernel 1: generate LoRA tables for all 4 tasks.
//   vec_a_t : [4][RANK][OUT_F]  (TRANSPOSED: a_t[t][r][o] = a[t][o][r])
//   vec_b   : [4][RANK][IN_F]   (natural Wb2 row order)
// Grid: 256 blocks x 256 threads. Blocks 0..127 -> gen_a, 128..255 -> gen_b.
// Each block: redundantly computes h[4][64] (cheap), then 4 threads per W2
// row (64 rows/block) each dot 16 of the 64 hidden dims, 2-stage shuffle
// reduce, lane q==0 writes the 4 task values.
// ---------------------------------------------------------------------------
__global__ __launch_bounds__(256) void gen_kernel(
    const float* __restrict__ task_emb,
    const float* __restrict__ Wa1, const float* __restrict__ ba1,
    const float* __restrict__ Wa2, const float* __restrict__ ba2,
    const float* __restrict__ Wb1, const float* __restrict__ bb1,
    const float* __restrict__ Wb2, const float* __restrict__ bb2,
    float* __restrict__ vec_a_t, float* __restrict__ vec_b)
{
    const int gen = blockIdx.x >> 7;             // 0 -> a, 1 -> b
    const int blk = blockIdx.x & 127;
    const float* __restrict__ W1 = gen ? Wb1 : Wa1;
    const float* __restrict__ b1 = gen ? bb1 : ba1;
    const float* __restrict__ W2 = gen ? Wb2 : Wa2;
    const float* __restrict__ b2 = gen ? bb2 : ba2;

    __shared__ float hs[4][HID];
    {
        const int j = threadIdx.x >> 2;          // hidden unit 0..63
        const int t = threadIdx.x & 3;           // task 0..3
        const float4* te = (const float4*)(task_emb + t * TASK_D);
        const float4* w  = (const float4*)(W1 + j * TASK_D);
        float acc = 0.f;
        #pragma unroll
        for (int d = 0; d < TASK_D / 4; ++d) {
            float4 a = te[d], b = w[d];
            acc += a.x * b.x + a.y * b.y + a.z * b.z + a.w * b.w;
        }
        hs[t][j] = gelu_exact(acc + b1[j]);
    }
    __syncthreads();

    const int lrow = threadIdx.x >> 2;           // 0..63  (W2 row within block)
    const int q    = threadIdx.x & 3;            // quarter of the 64 hidden dims
    const int o    = blk * 64 + lrow;            // W2 row 0..8191

    const float4* w2 = (const float4*)(W2 + (size_t)o * HID + q * 16);
    float acc0 = 0.f, acc1 = 0.f, acc2 = 0.f, acc3 = 0.f;
    #pragma unroll
    for (int k = 0; k < 4; ++k) {
        float4 w = w2[k];
        const int kb = q * 16 + k * 4;
        acc0 += hs[0][kb] * w.x + hs[0][kb+1] * w.y + hs[0][kb+2] * w.z + hs[0][kb+3] * w.w;
        acc1 += hs[1][kb] * w.x + hs[1][kb+1] * w.y + hs[1][kb+2] * w.z + hs[1][kb+3] * w.w;
        acc2 += hs[2][kb] * w.x + hs[2][kb+1] * w.y + hs[2][kb+2] * w.z + hs[2][kb+3] * w.w;
        acc3 += hs[3][kb] * w.x + hs[3][kb+1] * w.y + hs[3][kb+2] * w.z + hs[3][kb+3] * w.w;
    }
    #pragma unroll
    for (int off = 1; off <= 2; off <<= 1) {
        acc0 += __shfl_xor(acc0, off, 64);
        acc1 += __shfl_xor(acc1, off, 64);
        acc2 += __shfl_xor(acc2, off, 64);
        acc3 += __shfl_xor(acc3, off, 64);
    }
    if (q == 0) {
        const float bb = b2[o];
        float v[4] = { acc0 + bb, acc1 + bb, acc2 + bb, acc3 + bb };
        if (gen == 0) {
            const int oo = o >> 3, r = o & 7;    // vec_a row o -> (out oo, rank r)
            #pragma unroll
            for (int t = 0; t < 4; ++t)
                vec_a_t[t * (RANK * OUT_F) + r * OUT_F + oo] = v[t];
        } else {
            #pragma unroll
            for (int t = 0; t < 4; ++t)
                vec_b[t * (RANK * IN_F) + o] = v[t];
        }
    }
}

// ---------------------------------------------------------------------------
// Kernel 2: fused LoRA apply. One task per block; vec_b[t] staged in LDS.
// Grid = b_eff/8 blocks x 256 threads (4 waves); each wave handles 2 rows.
//   phase 1: tmp[i][r] = sum_k x[row,k]*b[t,r,k]   (LDS b, butterfly reduce)
//   phase 2: out[row,o] = base_out[row,o] + sum_r tmp[i][r]*a_t[t][r][o]
// a-fragments (registers, coalesced float4 from L2) amortized over both rows.
// ---------------------------------------------------------------------------
__global__ __launch_bounds__(256) void apply_kernel(
    const float* __restrict__ x, const float* __restrict__ base_out,
    const float* __restrict__ vec_a_t, const float* __restrict__ vec_b,
    float* __restrict__ out)
{
    const int t    = blockIdx.x & 3;             // task
    const int g    = blockIdx.x >> 2;            // group within task
    const int wave = threadIdx.x >> 6;
    const int lane = threadIdx.x & 63;

    __shared__ float bs[RANK * IN_F];            // 32 KB
    {
        const float4* src = (const float4*)(vec_b + (size_t)t * (RANK * IN_F));
        float4* dst = (float4*)bs;
        #pragma unroll
        for (int i = 0; i < 8; ++i)
            dst[threadIdx.x + 256 * i] = src[threadIdx.x + 256 * i];
    }
    __syncthreads();

    const int jbase = g * 8 + wave * 2;          // row index / 4
    float tmp[2][RANK];

    #pragma unroll
    for (int i = 0; i < 2; ++i) {
        const int row = t + 4 * (jbase + i);
        const float* __restrict__ xr = x + (size_t)row * IN_F;
        float4 xv[4];
        #pragma unroll
        for (int c = 0; c < 4; ++c)
            xv[c] = *(const float4*)(xr + c * 256 + lane * 4);

        float acc[RANK];
        #pragma unroll
        for (int r = 0; r < RANK; ++r) acc[r] = 0.f;
        #pragma unroll
        for (int c = 0; c < 4; ++c) {
            const int k = c * 256 + lane * 4;
            #pragma unroll
            for (int r = 0; r < RANK; ++r) {
                const float4 bv = *(const float4*)(bs + r * IN_F + k);
                acc[r] += xv[c].x * bv.x + xv[c].y * bv.y + xv[c].z * bv.z + xv[c].w * bv.w;
            }
        }
        #pragma unroll
        for (int off = 32; off > 0; off >>= 1) {
            #pragma unroll
            for (int r = 0; r < RANK; ++r)
                acc[r] += __shfl_xor(acc[r], off, 64);
        }
        #pragma unroll
        for (int r = 0; r < RANK; ++r) tmp[i][r] = acc[r];
    }

    const float* __restrict__ at = vec_a_t + (size_t)t * (RANK * OUT_F);
    #pragma unroll
    for (int c = 0; c < 4; ++c) {
        const int o = c * 256 + lane * 4;
        float4 af[RANK];
        #pragma unroll
        for (int r = 0; r < RANK; ++r)
            af[r] = *(const float4*)(at + r * OUT_F + o);
        #pragma unroll
        for (int i = 0; i < 2; ++i) {
            const int row = t + 4 * (jbase + i);
            const float4 bo = *(const float4*)(base_out + (size_t)row * OUT_F + o);
            float4 rv;
            rv.x = bo.x; rv.y = bo.y; rv.z = bo.z; rv.w = bo.w;
            #pragma unroll
            for (int r = 0; r < RANK; ++r) {
                rv.x += tmp[i][r] * af[r].x;
                rv.y += tmp[i][r] * af[r].y;
                rv.z += tmp[i][r] * af[r].z;
                rv.w += tmp[i][r] * af[r].w;
            }
            *(float4*)(out + (size_t)row * OUT_F + o) = rv;
        }
    }
}

extern "C" void kernel_launch(void* const* d_in, const int* in_sizes, int n_in,
                              void* d_out, int out_size, void* d_ws, size_t ws_size,
                              hipStream_t stream) {
    const float* x        = (const float*)d_in[0];
    const float* base_out = (const float*)d_in[1];
    const float* task_emb = (const float*)d_in[2];
    const float* Wa1      = (const float*)d_in[3];
    const float* ba1      = (const float*)d_in[4];
    const float* Wa2      = (const float*)d_in[5];
    const float* ba2      = (const float*)d_in[6];
    const float* Wb1      = (const float*)d_in[7];
    const float* bb1      = (const float*)d_in[8];
    const float* Wb2      = (const float*)d_in[9];
    const float* bb2      = (const float*)d_in[10];
    float* out = (float*)d_out;

    float* vec_a_t = (float*)d_ws;                        // 4*8192 floats
    float* vec_b   = vec_a_t + 4 * RANK * OUT_F;          // 4*8192 floats

    const int b_eff = in_sizes[0] / IN_F;                 // 8192

    gen_kernel<<<256, 256, 0, stream>>>(task_emb, Wa1, ba1, Wa2, ba2,
                                        Wb1, bb1, Wb2, bb2, vec_a_t, vec_b);
    apply_kernel<<<b_eff / 8, 256, 0, stream>>>(x, base_out, vec_a_t, vec_b, out);
}